// Round 3
// baseline (137449.744 us; speedup 1.0000x reference)
//
#include <hip/hip_runtime.h>
#include <hip/hip_cooperative_groups.h>
#include <float.h>

namespace cg = cooperative_groups;

// Problem constants (fixed shapes from setup_inputs)
#define NN 4096      // b*n
#define DD 640       // d
#define DE 512       // embed/inner dim
#define NPAN 256     // 16-wide panels
#define SB 128       // solve block
#define NSB (NN/SB)  // 32 solve blocks
#define GBLK 256     // cooperative grid blocks (1 block/CU)

static __device__ __forceinline__ float4 ldg4(const float* p) { return *(const float4*)p; }

// ---------------------------------------------------------------------------
// 1) q = xe@Wq, k = xe@Wk  (xe = xf[:, :512], ld 640). Fused dual GEMM.
// ---------------------------------------------------------------------------
__global__ __launch_bounds__(256) void proj_gemm(
    const float* __restrict__ xf, const float* __restrict__ Wq,
    const float* __restrict__ Wk, float* __restrict__ q, float* __restrict__ kk_)
{
  __shared__ float Xs[32][68], Qs[32][68], Ks[32][68];
  const int i0 = blockIdx.x * 64, c0 = blockIdx.y * 64;
  const int t = threadIdx.x, tr = t >> 4, tc = t & 15;
  float accq[4][4] = {}, acck[4][4] = {};
  for (int kb = 0; kb < DE; kb += 32) {
    {
      int m = t >> 3, k4 = (t & 7) << 2;
      float4 v0 = ldg4(xf + (size_t)(i0 + m) * DD + kb + k4);
      float4 v1 = ldg4(xf + (size_t)(i0 + m + 32) * DD + kb + k4);
      Xs[k4+0][m] = v0.x; Xs[k4+1][m] = v0.y; Xs[k4+2][m] = v0.z; Xs[k4+3][m] = v0.w;
      Xs[k4+0][m+32] = v1.x; Xs[k4+1][m+32] = v1.y; Xs[k4+2][m+32] = v1.z; Xs[k4+3][m+32] = v1.w;
    }
    {
      int kr = t >> 3, n8 = (t & 7) << 3;
      *(float4*)&Qs[kr][n8]   = ldg4(Wq + (size_t)(kb + kr) * DE + c0 + n8);
      *(float4*)&Qs[kr][n8+4] = ldg4(Wq + (size_t)(kb + kr) * DE + c0 + n8 + 4);
      *(float4*)&Ks[kr][n8]   = ldg4(Wk + (size_t)(kb + kr) * DE + c0 + n8);
      *(float4*)&Ks[kr][n8+4] = ldg4(Wk + (size_t)(kb + kr) * DE + c0 + n8 + 4);
    }
    __syncthreads();
    #pragma unroll
    for (int kkk = 0; kkk < 32; ++kkk) {
      float a[4], bq[4], bk[4];
      *(float4*)a  = *(const float4*)&Xs[kkk][tr << 2];
      *(float4*)bq = *(const float4*)&Qs[kkk][tc << 2];
      *(float4*)bk = *(const float4*)&Ks[kkk][tc << 2];
      #pragma unroll
      for (int r = 0; r < 4; ++r)
        #pragma unroll
        for (int c = 0; c < 4; ++c) { accq[r][c] += a[r]*bq[c]; acck[r][c] += a[r]*bk[c]; }
    }
    __syncthreads();
  }
  #pragma unroll
  for (int r = 0; r < 4; ++r) {
    float* qp = q   + (size_t)(i0 + (tr<<2) + r) * DE + c0 + (tc<<2);
    float* kp = kk_ + (size_t)(i0 + (tr<<2) + r) * DE + c0 + (tc<<2);
    *(float4*)qp = make_float4(accq[r][0], accq[r][1], accq[r][2], accq[r][3]);
    *(float4*)kp = make_float4(acck[r][0], acck[r][1], acck[r][2], acck[r][3]);
  }
}

// ---------------------------------------------------------------------------
// 2) row squared norms
// ---------------------------------------------------------------------------
__global__ __launch_bounds__(256) void rownorm(
    const float* __restrict__ q, const float* __restrict__ kk_,
    float* __restrict__ q2, float* __restrict__ k2)
{
  int w = (blockIdx.x * 256 + threadIdx.x) >> 6;
  int lane = threadIdx.x & 63;
  const float* src = (w < NN) ? q : kk_;
  int row = (w < NN) ? w : w - NN;
  const float* p = src + (size_t)row * DE;
  float s = 0.f;
  for (int c = lane; c < DE; c += 64) { float v = p[c]; s += v * v; }
  for (int off = 32; off; off >>= 1) s += __shfl_down(s, off);
  if (lane == 0) { if (w < NN) q2[row] = s; else k2[row] = s; }
}

// ---------------------------------------------------------------------------
// 3) dots = (q2[i]+k2[j]-2*q@k^T)/DE
// ---------------------------------------------------------------------------
__global__ __launch_bounds__(256) void dots_gemm(
    const float* __restrict__ q, const float* __restrict__ kk_,
    const float* __restrict__ q2, const float* __restrict__ k2,
    float* __restrict__ dots)
{
  __shared__ float Qs[32][68], Ks[32][68];
  const int i0 = blockIdx.x * 64, j0 = blockIdx.y * 64;
  const int t = threadIdx.x, tr = t >> 4, tc = t & 15;
  float acc[4][4] = {};
  for (int kb = 0; kb < DE; kb += 32) {
    int m = t >> 3, k4 = (t & 7) << 2;
    {
      float4 v0 = ldg4(q + (size_t)(i0 + m) * DE + kb + k4);
      float4 v1 = ldg4(q + (size_t)(i0 + m + 32) * DE + kb + k4);
      Qs[k4+0][m] = v0.x; Qs[k4+1][m] = v0.y; Qs[k4+2][m] = v0.z; Qs[k4+3][m] = v0.w;
      Qs[k4+0][m+32] = v1.x; Qs[k4+1][m+32] = v1.y; Qs[k4+2][m+32] = v1.z; Qs[k4+3][m+32] = v1.w;
    }
    {
      float4 v0 = ldg4(kk_ + (size_t)(j0 + m) * DE + kb + k4);
      float4 v1 = ldg4(kk_ + (size_t)(j0 + m + 32) * DE + kb + k4);
      Ks[k4+0][m] = v0.x; Ks[k4+1][m] = v0.y; Ks[k4+2][m] = v0.z; Ks[k4+3][m] = v0.w;
      Ks[k4+0][m+32] = v1.x; Ks[k4+1][m+32] = v1.y; Ks[k4+2][m+32] = v1.z; Ks[k4+3][m+32] = v1.w;
    }
    __syncthreads();
    #pragma unroll
    for (int kkk = 0; kkk < 32; ++kkk) {
      float a[4], b[4];
      *(float4*)a = *(const float4*)&Qs[kkk][tr << 2];
      *(float4*)b = *(const float4*)&Ks[kkk][tc << 2];
      #pragma unroll
      for (int r = 0; r < 4; ++r)
        #pragma unroll
        for (int c = 0; c < 4; ++c) acc[r][c] += a[r]*b[c];
    }
    __syncthreads();
  }
  const float inv = 1.0f / (float)DE;
  float k2v[4]; *(float4*)k2v = ldg4(k2 + j0 + (tc<<2));
  #pragma unroll
  for (int r = 0; r < 4; ++r) {
    float q2v = q2[i0 + (tr<<2) + r];
    float o[4];
    #pragma unroll
    for (int c = 0; c < 4; ++c) o[c] = (q2v + k2v[c] - 2.0f*acc[r][c]) * inv;
    *(float4*)(dots + (size_t)(i0 + (tr<<2) + r) * NN + j0 + (tc<<2)) =
        make_float4(o[0], o[1], o[2], o[3]);
  }
}

// ---------------------------------------------------------------------------
// 4) per-row top-64 -> bit mask rows
// ---------------------------------------------------------------------------
__global__ __launch_bounds__(256) void topk_bits(
    const float* __restrict__ dots, unsigned int* __restrict__ bits)
{
  __shared__ float row[NN];
  __shared__ unsigned int b[128];
  __shared__ float rv[4]; __shared__ int ri[4];
  const int i = blockIdx.x, t = threadIdx.x;
  const float* dr = dots + (size_t)i * NN;
  for (int c = t; c < NN; c += 256) row[c] = dr[c];
  if (t < 128) b[t] = 0u;
  __syncthreads();
  for (int it = 0; it < 64; ++it) {
    float bv = -FLT_MAX; int bi = NN;
    for (int c = t; c < NN; c += 256) { float v = row[c]; if (v > bv) { bv = v; bi = c; } }
    for (int off = 32; off; off >>= 1) {
      float ov = __shfl_down(bv, off); int oi = __shfl_down(bi, off);
      if (ov > bv || (ov == bv && oi < bi)) { bv = ov; bi = oi; }
    }
    if ((t & 63) == 0) { rv[t >> 6] = bv; ri[t >> 6] = bi; }
    __syncthreads();
    if (t == 0) {
      float fv = rv[0]; int fi = ri[0];
      for (int w = 1; w < 4; ++w)
        if (rv[w] > fv || (rv[w] == fv && ri[w] < fi)) { fv = rv[w]; fi = ri[w]; }
      b[fi >> 5] |= 1u << (fi & 31);
      row[fi] = -FLT_MAX;
    }
    __syncthreads();
  }
  if (t < 128) bits[(size_t)i * 128 + t] = b[t];
}

// ---------------------------------------------------------------------------
// 5) A = I - alpha * dots * (bit(i,j)|bit(j,i)), in place over dots.
// ---------------------------------------------------------------------------
__global__ __launch_bounds__(256) void build_A(
    float* __restrict__ A, const unsigned int* __restrict__ bits,
    const float* __restrict__ alpha_p)
{
  int tid = blockIdx.x * 256 + threadIdx.x;
  int i = tid >> 10;
  int j4 = (tid & 1023) << 2;
  float alpha = alpha_p[0];
  float* p = A + (size_t)i * NN + j4;
  float4 d = *(float4*)p;
  unsigned int wrow = bits[(size_t)i * 128 + (j4 >> 5)];
  float dv[4] = {d.x, d.y, d.z, d.w}, o[4];
  #pragma unroll
  for (int u = 0; u < 4; ++u) {
    int j = j4 + u;
    unsigned int m1 = (wrow >> (j & 31)) & 1u;
    unsigned int m2 = (bits[(size_t)j * 128 + (i >> 5)] >> (i & 31)) & 1u;
    float base = (i == j) ? 1.0f : 0.0f;
    o[u] = base - ((m1 | m2) ? alpha * dv[u] : 0.0f);
  }
  *(float4*)p = make_float4(o[0], o[1], o[2], o[3]);
}

// ---------------------------------------------------------------------------
// 6) register-resident 16-col panel factorization with partial pivoting.
//    Virtual pivoting: only the perm_s entries swap; data stays put.
//    Thread t owns logical rows k0f + t + 1024*i (i=0..3) of the strip.
// ---------------------------------------------------------------------------
__device__ __forceinline__ void factor16(
    float (&a)[4][16], int k0f, int Mf,
    int* perm_s, float (&l11)[16][17],
    float* bufA, float* bufB, float* rv, int* ri, int* s_pr)
{
  const int t = threadIdx.x;
  #pragma unroll
  for (int j = 0; j < 16; ++j) {
    float bv = -1.0f; int br = 1 << 30;
    #pragma unroll
    for (int i = 0; i < 4; ++i) {
      int r = t + (i << 10);
      if (r >= j && r < Mf) {
        float v = fabsf(a[i][j]);
        if (v > bv || (v == bv && r < br)) { bv = v; br = r; }
      }
    }
    #pragma unroll
    for (int off = 32; off; off >>= 1) {
      float ov = __shfl_down(bv, off); int orr = __shfl_down(br, off);
      if (ov > bv || (ov == bv && orr < br)) { bv = ov; br = orr; }
    }
    if ((t & 63) == 0) { rv[t >> 6] = bv; ri[t >> 6] = br; }
    __syncthreads();
    if (t == 0) {
      float fv = rv[0]; int fr = ri[0];
      for (int w = 1; w < 16; ++w)
        if (rv[w] > fv || (rv[w] == fv && ri[w] < fr)) { fv = rv[w]; fr = ri[w]; }
      *s_pr = fr;
      if (fr != j) {
        int tmp = perm_s[k0f + j];
        perm_s[k0f + j] = perm_s[k0f + fr];
        perm_s[k0f + fr] = tmp;
      }
    }
    __syncthreads();
    const int pr = *s_pr, prT = pr & 1023, prS = pr >> 10;
    if (t == prT) {
      #pragma unroll
      for (int i2 = 0; i2 < 4; ++i2) if (i2 == prS) {
        #pragma unroll
        for (int c = 0; c < 16; ++c) bufB[c] = a[i2][c];
      }
    }
    if (t == j) {
      #pragma unroll
      for (int c = 0; c < 16; ++c) bufA[c] = a[0][c];
    }
    __syncthreads();
    if (t == j) {
      #pragma unroll
      for (int c = 0; c < 16; ++c) a[0][c] = bufB[c];
    }
    if (t == prT) {
      #pragma unroll
      for (int i2 = 0; i2 < 4; ++i2) if (i2 == prS) {
        #pragma unroll
        for (int c = 0; c < 16; ++c) a[i2][c] = bufA[c];
      }
    }
    float rp = 1.0f / bufB[j];
    #pragma unroll
    for (int i = 0; i < 4; ++i) {
      int r = t + (i << 10);
      if (r > j && r < Mf) {
        float mlt = a[i][j] * rp;
        a[i][j] = mlt;
        #pragma unroll
        for (int c = j + 1; c < 16; ++c) a[i][c] -= mlt * bufB[c];
      }
    }
    __syncthreads();
  }
  if (t < 16) {
    #pragma unroll
    for (int c = 0; c < 16; ++c) l11[t][c] = a[0][c];
  }
  __syncthreads();
}

// ---------------------------------------------------------------------------
// 7) the whole LU as ONE cooperative kernel. 256 blocks x 1024 threads.
//    Block 0: lookahead strip (trsm + rank-16 update + factor next panel).
//    Blocks 1..255: rank-16 trailing update of 16-col chunks (redundant
//    local 16x16 trsm per chunk). One grid.sync per panel.
//    perm ping-pong: panel q's state lives in permg + (q&1)*NN.
// ---------------------------------------------------------------------------
__global__ __launch_bounds__(1024, 4) void lu_coop(
    float* __restrict__ A, int* __restrict__ permg)
{
  __shared__ int perm_s[NN];          // block 0's authoritative perm (16 KB)
  __shared__ float l11s[16][17];
  __shared__ float u12s[16][20];      // row stride 20 -> 16B-aligned float4 rows
  __shared__ float bufA[16], bufB[16];
  __shared__ float rv[16]; __shared__ int ri[16];
  __shared__ int s_pr;

  const int t = threadIdx.x;
  const int b = blockIdx.x;
  cg::grid_group grid = cg::this_grid();
  float a[4][16];

  if (b == 0) {
    for (int r = t; r < NN; r += 1024) perm_s[r] = r;
    __syncthreads();
    #pragma unroll
    for (int i = 0; i < 4; ++i) {
      int r = t + (i << 10);
      const float* src = A + (size_t)r * NN;
      #pragma unroll
      for (int c4 = 0; c4 < 16; c4 += 4) {
        float4 v = ldg4(src + c4);
        a[i][c4] = v.x; a[i][c4+1] = v.y; a[i][c4+2] = v.z; a[i][c4+3] = v.w;
      }
    }
    factor16(a, 0, NN, perm_s, l11s, bufA, bufB, rv, ri, &s_pr);
    #pragma unroll
    for (int i = 0; i < 4; ++i) {
      int r = t + (i << 10);
      float* dst = A + (size_t)perm_s[r] * NN;
      #pragma unroll
      for (int c4 = 0; c4 < 16; c4 += 4)
        *(float4*)(dst + c4) = make_float4(a[i][c4], a[i][c4+1], a[i][c4+2], a[i][c4+3]);
    }
    for (int r = t; r < NN; r += 1024) permg[r] = perm_s[r];   // buf0 = panel-0 state
  }
  __threadfence();
  grid.sync();

  for (int p = 0; p < NPAN - 1; ++p) {
    const int k0 = p << 4, kS = k0 + 16, M2 = NN - kS;
    if (b == 0) {
      // --- trsm for the lookahead strip cols [kS, kS+16) ---
      if (t < 256) {
        int jj = t >> 4, cc = t & 15;
        u12s[jj][cc] = A[(size_t)perm_s[k0 + jj] * NN + kS + cc];
      }
      __syncthreads();
      if (t < 16) {
        float x[16];
        #pragma unroll
        for (int j = 0; j < 16; ++j) x[j] = u12s[j][t];
        #pragma unroll
        for (int j = 1; j < 16; ++j) {
          float s = x[j];
          #pragma unroll
          for (int jj = 0; jj < 16; ++jj) if (jj < j) s -= l11s[j][jj] * x[jj];
          x[j] = s;
        }
        #pragma unroll
        for (int j = 0; j < 16; ++j) {
          u12s[j][t] = x[j];
          A[(size_t)perm_s[k0 + j] * NN + kS + t] = x[j];
        }
      }
      __syncthreads();
      // --- rank-16 update of the strip, result straight into regs a ---
      #pragma unroll
      for (int ps = 0; ps < 2; ++ps) {
        int r0r = t + ((2 * ps) << 10), r1r = r0r + 1024;
        bool v0 = r0r < M2, v1 = r1r < M2;
        float L0[16], L1[16];
        if (v0) {
          size_t ph = (size_t)perm_s[kS + r0r];
          const float* Lp = A + ph * NN + k0;
          const float* Cp = A + ph * NN + kS;
          #pragma unroll
          for (int c4 = 0; c4 < 16; c4 += 4) {
            float4 lv = ldg4(Lp + c4);
            L0[c4]=lv.x; L0[c4+1]=lv.y; L0[c4+2]=lv.z; L0[c4+3]=lv.w;
            float4 cv = ldg4(Cp + c4);
            a[2*ps][c4]=cv.x; a[2*ps][c4+1]=cv.y; a[2*ps][c4+2]=cv.z; a[2*ps][c4+3]=cv.w;
          }
        }
        if (v1) {
          size_t ph = (size_t)perm_s[kS + r1r];
          const float* Lp = A + ph * NN + k0;
          const float* Cp = A + ph * NN + kS;
          #pragma unroll
          for (int c4 = 0; c4 < 16; c4 += 4) {
            float4 lv = ldg4(Lp + c4);
            L1[c4]=lv.x; L1[c4+1]=lv.y; L1[c4+2]=lv.z; L1[c4+3]=lv.w;
            float4 cv = ldg4(Cp + c4);
            a[2*ps+1][c4]=cv.x; a[2*ps+1][c4+1]=cv.y; a[2*ps+1][c4+2]=cv.z; a[2*ps+1][c4+3]=cv.w;
          }
        }
        #pragma unroll
        for (int j = 0; j < 16; ++j) {
          #pragma unroll
          for (int c4 = 0; c4 < 16; c4 += 4) {
            float4 u4 = *(const float4*)&u12s[j][c4];
            a[2*ps][c4]     -= L0[j] * u4.x;
            a[2*ps][c4+1]   -= L0[j] * u4.y;
            a[2*ps][c4+2]   -= L0[j] * u4.z;
            a[2*ps][c4+3]   -= L0[j] * u4.w;
            a[2*ps+1][c4]   -= L1[j] * u4.x;
            a[2*ps+1][c4+1] -= L1[j] * u4.y;
            a[2*ps+1][c4+2] -= L1[j] * u4.z;
            a[2*ps+1][c4+3] -= L1[j] * u4.w;
          }
        }
      }
      // --- factor panel p+1 in registers ---
      factor16(a, kS, M2, perm_s, l11s, bufA, bufB, rv, ri, &s_pr);
      // --- writeback factored strip ---
      #pragma unroll
      for (int i = 0; i < 4; ++i) {
        int rr = t + (i << 10);
        if (rr < M2) {
          float* dst = A + (size_t)perm_s[kS + rr] * NN + kS;
          #pragma unroll
          for (int c4 = 0; c4 < 16; c4 += 4)
            *(float4*)(dst + c4) = make_float4(a[i][c4], a[i][c4+1], a[i][c4+2], a[i][c4+3]);
        }
      }
      // --- publish panel (p+1) perm state to the other buffer ---
      int* dstp = permg + (((p + 1) & 1) ? NN : 0);
      for (int r = t; r < NN; r += 1024) dstp[r] = perm_s[r];
    } else {
      const int* pg = permg + ((p & 1) ? NN : 0);   // panel-p perm state
      for (int cb = b - 1; ; cb += (GBLK - 1)) {
        int c0 = k0 + 32 + cb * 16;
        if (c0 >= NN) break;
        if (t < 256) {
          int jj = t >> 4, cc = t & 15;
          int prw = pg[k0 + jj];
          l11s[jj][cc] = A[(size_t)prw * NN + k0 + cc];
          u12s[jj][cc] = A[(size_t)prw * NN + c0 + cc];
        }
        __syncthreads();
        if (t < 16) {
          float x[16];
          #pragma unroll
          for (int j = 0; j < 16; ++j) x[j] = u12s[j][t];
          #pragma unroll
          for (int j = 1; j < 16; ++j) {
            float s = x[j];
            #pragma unroll
            for (int jj = 0; jj < 16; ++jj) if (jj < j) s -= l11s[j][jj] * x[jj];
            x[j] = s;
          }
          #pragma unroll
          for (int j = 0; j < 16; ++j) {
            u12s[j][t] = x[j];
            A[(size_t)pg[k0 + j] * NN + c0 + t] = x[j];
          }
        }
        __syncthreads();
        #pragma unroll
        for (int ps = 0; ps < 2; ++ps) {
          int r0r = t + ((2 * ps) << 10), r1r = r0r + 1024;
          bool v0 = r0r < M2, v1 = r1r < M2;
          float L0[16], L1[16], C0[16], C1[16];
          size_t ph0 = 0, ph1 = 0;
          if (v0) {
            ph0 = (size_t)pg[kS + r0r];
            const float* Lp = A + ph0 * NN + k0;
            const float* Cp = A + ph0 * NN + c0;
            #pragma unroll
            for (int c4 = 0; c4 < 16; c4 += 4) {
              float4 lv = ldg4(Lp + c4);
              L0[c4]=lv.x; L0[c4+1]=lv.y; L0[c4+2]=lv.z; L0[c4+3]=lv.w;
              float4 cv = ldg4(Cp + c4);
              C0[c4]=cv.x; C0[c4+1]=cv.y; C0[c4+2]=cv.z; C0[c4+3]=cv.w;
            }
          }
          if (v1) {
            ph1 = (size_t)pg[kS + r1r];
            const float* Lp = A + ph1 * NN + k0;
            const float* Cp = A + ph1 * NN + c0;
            #pragma unroll
            for (int c4 = 0; c4 < 16; c4 += 4) {
              float4 lv = ldg4(Lp + c4);
              L1[c4]=lv.x; L1[c4+1]=lv.y; L1[c4+2]=lv.z; L1[c4+3]=lv.w;
              float4 cv = ldg4(Cp + c4);
              C1[c4]=cv.x; C1[c4+1]=cv.y; C1[c4+2]=cv.z; C1[c4+3]=cv.w;
            }
          }
          #pragma unroll
          for (int j = 0; j < 16; ++j) {
            #pragma unroll
            for (int c4 = 0; c4 < 16; c4 += 4) {
              float4 u4 = *(const float4*)&u12s[j][c4];
              C0[c4]   -= L0[j] * u4.x; C0[c4+1] -= L0[j] * u4.y;
              C0[c4+2] -= L0[j] * u4.z; C0[c4+3] -= L0[j] * u4.w;
              C1[c4]   -= L1[j] * u4.x; C1[c4+1] -= L1[j] * u4.y;
              C1[c4+2] -= L1[j] * u4.z; C1[c4+3] -= L1[j] * u4.w;
            }
          }
          if (v0) {
            float* Cp = A + ph0 * NN + c0;
            #pragma unroll
            for (int c4 = 0; c4 < 16; c4 += 4)
              *(float4*)(Cp + c4) = make_float4(C0[c4], C0[c4+1], C0[c4+2], C0[c4+3]);
          }
          if (v1) {
            float* Cp = A + ph1 * NN + c0;
            #pragma unroll
            for (int c4 = 0; c4 < 16; c4 += 4)
              *(float4*)(Cp + c4) = make_float4(C1[c4], C1[c4+1], C1[c4+2], C1[c4+3]);
          }
        }
        __syncthreads();
      }
    }
    __threadfence();
    grid.sync();
  }
}

// ---------------------------------------------------------------------------
// 8) invert the 32 diagonal 128x128 blocks of L (unit lower) / U (upper),
//    reading A rows through the final perm.
// ---------------------------------------------------------------------------
__global__ __launch_bounds__(128) void inv_tri(
    const float* __restrict__ Ag, const int* __restrict__ perm,
    float* __restrict__ invT, int upper)
{
  __shared__ float xs[128][128];
  const int s = blockIdx.x, t = threadIdx.x;
  const int r0 = s * SB;
  for (int i = 0; i < 128; ++i) xs[i][t] = 0.0f;
  if (!upper) {
    xs[t][t] = 1.0f;
    for (int i = 1; i < 128; ++i) {
      const float* Ti = Ag + (size_t)perm[r0 + i] * NN + r0;
      float ssum = 0.f;
      for (int j = 0; j < i; ++j) ssum += Ti[j] * xs[j][t];
      if (i != t) xs[i][t] = -ssum;
    }
  } else {
    { const float* Tt = Ag + (size_t)perm[r0 + t] * NN + r0; xs[t][t] = 1.0f / Tt[t]; }
    for (int i = 126; i >= 0; --i) {
      const float* Ti = Ag + (size_t)perm[r0 + i] * NN + r0;
      float ssum = 0.f;
      for (int j = i + 1; j < 128; ++j) ssum += Ti[j] * xs[j][t];
      if (i != t) xs[i][t] = -ssum / Ti[i];
    }
  }
  for (int i = 0; i < 128; ++i) invT[(size_t)s * SB * SB + (size_t)i * SB + t] = xs[i][t];
}

// ---------------------------------------------------------------------------
// 9) C -= A(perm rows) * B   (64x64 tile, KT=32; K multiple of 32).
// ---------------------------------------------------------------------------
__global__ __launch_bounds__(256) void rank_update(
    float* __restrict__ C, int ldc,
    const float* __restrict__ Ab, int rowoff, int coloff,
    const int* __restrict__ perm,
    const float* __restrict__ Bop, int ldb,
    int Mr, int Nc, int K)
{
  __shared__ float As[32][68], Bs[32][68];
  const int m0 = blockIdx.x * 64, n0 = blockIdx.y * 64;
  const int t = threadIdx.x, tr = t >> 4, tc = t & 15;
  const float4 z4 = make_float4(0.f, 0.f, 0.f, 0.f);
  float acc[4][4] = {};
  for (int kb = 0; kb < K; kb += 32) {
    {
      int m = t >> 3, k4 = (t & 7) << 2;
      int row0 = m0 + m, row1 = m0 + m + 32;
      float4 v0 = z4, v1 = z4;
      if (row0 < Mr) v0 = ldg4(Ab + (size_t)perm[rowoff + row0] * NN + coloff + kb + k4);
      if (row1 < Mr) v1 = ldg4(Ab + (size_t)perm[rowoff + row1] * NN + coloff + kb + k4);
      As[k4+0][m] = v0.x; As[k4+1][m] = v0.y; As[k4+2][m] = v0.z; As[k4+3][m] = v0.w;
      As[k4+0][m+32] = v1.x; As[k4+1][m+32] = v1.y; As[k4+2][m+32] = v1.z; As[k4+3][m+32] = v1.w;
    }
    {
      int kr = t >> 3, n8 = (t & 7) << 3;
      bool ok = (n0 + n8 < Nc);
      float4 w0 = ok ? ldg4(Bop + (size_t)(kb + kr) * ldb + n0 + n8) : z4;
      float4 w1 = ok ? ldg4(Bop + (size_t)(kb + kr) * ldb + n0 + n8 + 4) : z4;
      *(float4*)&Bs[kr][n8] = w0; *(float4*)&Bs[kr][n8+4] = w1;
    }
    __syncthreads();
    #pragma unroll
    for (int kkk = 0; kkk < 32; ++kkk) {
      float av[4], bvv[4];
      *(float4*)av = *(const float4*)&As[kkk][tr << 2];
      *(float4*)bvv = *(const float4*)&Bs[kkk][tc << 2];
      #pragma unroll
      for (int r = 0; r < 4; ++r)
        #pragma unroll
        for (int c = 0; c < 4; ++c) acc[r][c] += av[r] * bvv[c];
    }
    __syncthreads();
  }
  #pragma unroll
  for (int r = 0; r < 4; ++r) {
    int m = m0 + (tr << 2) + r;
    int n = n0 + (tc << 2);
    if (m < Mr && n < Nc) {
      float* cp = C + (size_t)m * ldc + n;
      float4 cv = *(float4*)cp;
      cv.x -= acc[r][0]; cv.y -= acc[r][1]; cv.z -= acc[r][2]; cv.w -= acc[r][3];
      *(float4*)cp = cv;
    }
  }
}

// 10) out[r][:] = xf[perm[r]][:]  (RHS permutation P b)
__global__ __launch_bounds__(256) void gather_rows(
    const float* __restrict__ xf, const int* __restrict__ perm, float* __restrict__ out)
{
  const int r = blockIdx.x, t = threadIdx.x;
  const int src = perm[r];
  const float4* s = (const float4*)(xf + (size_t)src * DD);
  float4* d = (float4*)(out + (size_t)r * DD);
  for (int c = t; c < DD / 4; c += 256) d[c] = s[c];
}

// ---------------------------------------------------------------------------
// 11) in-place diag block apply: B[r0:r0+128, :] = Minv(128x128) @ same.
// ---------------------------------------------------------------------------
__global__ __launch_bounds__(256) void diag_apply(
    float* __restrict__ B, const float* __restrict__ Minv, int r0)
{
  __shared__ float Bs[128][68];
  const int c0 = blockIdx.x * 64, t = threadIdx.x;
  #pragma unroll
  for (int v = 0; v < 8; ++v) {
    int id = t + v * 256;
    int k = id >> 4, c4 = (id & 15) << 2;
    *(float4*)&Bs[k][c4] = ldg4(B + (size_t)(r0 + k) * DD + c0 + c4);
  }
  __syncthreads();
  const int tr = t >> 4, tc = t & 15;
  float acc[8][4] = {};
  for (int k4 = 0; k4 < 128; k4 += 4) {
    float b0[4], b1[4], b2[4], b3[4];
    *(float4*)b0 = *(const float4*)&Bs[k4+0][tc << 2];
    *(float4*)b1 = *(const float4*)&Bs[k4+1][tc << 2];
    *(float4*)b2 = *(const float4*)&Bs[k4+2][tc << 2];
    *(float4*)b3 = *(const float4*)&Bs[k4+3][tc << 2];
    #pragma unroll
    for (int rr = 0; rr < 8; ++rr) {
      float m[4]; *(float4*)m = ldg4(Minv + (size_t)(tr*8 + rr) * SB + k4);
      #pragma unroll
      for (int c = 0; c < 4; ++c)
        acc[rr][c] += m[0]*b0[c] + m[1]*b1[c] + m[2]*b2[c] + m[3]*b3[c];
    }
  }
  #pragma unroll
  for (int rr = 0; rr < 8; ++rr)
    *(float4*)(B + (size_t)(r0 + tr*8 + rr) * DD + c0 + (tc << 2)) =
        make_float4(acc[rr][0], acc[rr][1], acc[rr][2], acc[rr][3]);
}

// ---------------------------------------------------------------------------
extern "C" void kernel_launch(void* const* d_in, const int* in_sizes, int n_in,
                              void* d_out, int out_size, void* d_ws, size_t ws_size,
                              hipStream_t stream)
{
  const float* xf    = (const float*)d_in[0];
  const float* Wq    = (const float*)d_in[1];
  const float* Wk    = (const float*)d_in[2];
  const float* alpha = (const float*)d_in[3];
  float* out = (float*)d_out;
  char* ws = (char*)d_ws;

  // workspace layout
  float* Amat = (float*)(ws);                          // 64 MB (dots -> A -> LU)
  float* q    = (float*)(ws + 67108864ull);            // 8 MB
  float* kbuf = (float*)(ws + 75497472ull);            // 8 MB
  float* invL = (float*)(ws + 83886080ull);            // 2 MB
  float* invU = (float*)(ws + 85983232ull);            // 2 MB
  unsigned int* bits = (unsigned int*)(ws + 88080384ull); // 2 MB
  float* q2   = (float*)(ws + 90177536ull);
  float* k2   = (float*)(ws + 90193920ull);
  int* permg  = (int*)(ws + 90210304ull);              // 2 x NN ints (ping-pong)
  int* permF  = permg + NN;                            // final = panel-255 state (odd)

  proj_gemm<<<dim3(NN/64, DE/64), 256, 0, stream>>>(xf, Wq, Wk, q, kbuf);
  rownorm<<<2 * NN / 4, 256, 0, stream>>>(q, kbuf, q2, k2);
  dots_gemm<<<dim3(NN/64, NN/64), 256, 0, stream>>>(q, kbuf, q2, k2, Amat);
  topk_bits<<<NN, 256, 0, stream>>>(Amat, bits);
  build_A<<<NN * NN / 4 / 256, 256, 0, stream>>>(Amat, bits, alpha);

  // the entire pivoted LU in one cooperative kernel
  {
    float* Ap = Amat; int* Pp = permg;
    void* kargs[] = { (void*)&Ap, (void*)&Pp };
    hipLaunchCooperativeKernel(reinterpret_cast<void*>(lu_coop),
                               dim3(GBLK), dim3(1024), kargs, 0, stream);
  }

  inv_tri<<<NSB, 128, 0, stream>>>(Amat, permF, invL, 0);
  inv_tri<<<NSB, 128, 0, stream>>>(Amat, permF, invU, 1);
  gather_rows<<<NN, 256, 0, stream>>>(xf, permF, out);

  // forward solve L y = P b
  for (int s = 0; s < NSB; ++s) {
    int r0 = s * SB;
    diag_apply<<<DD / 64, 256, 0, stream>>>(out, invL + (size_t)s * SB * SB, r0);
    if (r0 + SB < NN) {
      int M2 = NN - r0 - SB;
      rank_update<<<dim3(M2 / 64, DD / 64), 256, 0, stream>>>(
          out + (size_t)(r0 + SB) * DD, DD,
          Amat, r0 + SB, r0, permF,
          out + (size_t)r0 * DD, DD,
          M2, DD, SB);
    }
  }
  // backward solve U x = y
  for (int s = NSB - 1; s >= 0; --s) {
    int r0 = s * SB;
    diag_apply<<<DD / 64, 256, 0, stream>>>(out, invU + (size_t)s * SB * SB, r0);
    if (r0 > 0) {
      rank_update<<<dim3(r0 / 64, DD / 64), 256, 0, stream>>>(
          out, DD,
          Amat, 0, r0, permF,
          out + (size_t)r0 * DD, DD,
          r0, DD, SB);
    }
  }
}

// Round 4
// 65489.227 us; speedup vs baseline: 2.0988x; 2.0988x over previous
//
#include <hip/hip_runtime.h>
#include <hip/hip_cooperative_groups.h>
#include <float.h>

namespace cg = cooperative_groups;

// Problem constants (fixed shapes from setup_inputs)
#define NN 4096      // b*n
#define DD 640       // d
#define DE 512       // embed/inner dim
#define NPAN 256     // 16-wide panels
#define SB 128       // solve block
#define NSB (NN/SB)  // 32 solve blocks
#define GBLK 256     // cooperative grid blocks (1 block/CU)

static __device__ __forceinline__ float4 ldg4(const float* p) { return *(const float4*)p; }

// ---------------------------------------------------------------------------
// 1) q = xe@Wq, k = xe@Wk  (xe = xf[:, :512], ld 640). Fused dual GEMM.
// ---------------------------------------------------------------------------
__global__ __launch_bounds__(256) void proj_gemm(
    const float* __restrict__ xf, const float* __restrict__ Wq,
    const float* __restrict__ Wk, float* __restrict__ q, float* __restrict__ kk_)
{
  __shared__ float Xs[32][68], Qs[32][68], Ks[32][68];
  const int i0 = blockIdx.x * 64, c0 = blockIdx.y * 64;
  const int t = threadIdx.x, tr = t >> 4, tc = t & 15;
  float accq[4][4] = {}, acck[4][4] = {};
  for (int kb = 0; kb < DE; kb += 32) {
    {
      int m = t >> 3, k4 = (t & 7) << 2;
      float4 v0 = ldg4(xf + (size_t)(i0 + m) * DD + kb + k4);
      float4 v1 = ldg4(xf + (size_t)(i0 + m + 32) * DD + kb + k4);
      Xs[k4+0][m] = v0.x; Xs[k4+1][m] = v0.y; Xs[k4+2][m] = v0.z; Xs[k4+3][m] = v0.w;
      Xs[k4+0][m+32] = v1.x; Xs[k4+1][m+32] = v1.y; Xs[k4+2][m+32] = v1.z; Xs[k4+3][m+32] = v1.w;
    }
    {
      int kr = t >> 3, n8 = (t & 7) << 3;
      *(float4*)&Qs[kr][n8]   = ldg4(Wq + (size_t)(kb + kr) * DE + c0 + n8);
      *(float4*)&Qs[kr][n8+4] = ldg4(Wq + (size_t)(kb + kr) * DE + c0 + n8 + 4);
      *(float4*)&Ks[kr][n8]   = ldg4(Wk + (size_t)(kb + kr) * DE + c0 + n8);
      *(float4*)&Ks[kr][n8+4] = ldg4(Wk + (size_t)(kb + kr) * DE + c0 + n8 + 4);
    }
    __syncthreads();
    #pragma unroll
    for (int kkk = 0; kkk < 32; ++kkk) {
      float a[4], bq[4], bk[4];
      *(float4*)a  = *(const float4*)&Xs[kkk][tr << 2];
      *(float4*)bq = *(const float4*)&Qs[kkk][tc << 2];
      *(float4*)bk = *(const float4*)&Ks[kkk][tc << 2];
      #pragma unroll
      for (int r = 0; r < 4; ++r)
        #pragma unroll
        for (int c = 0; c < 4; ++c) { accq[r][c] += a[r]*bq[c]; acck[r][c] += a[r]*bk[c]; }
    }
    __syncthreads();
  }
  #pragma unroll
  for (int r = 0; r < 4; ++r) {
    float* qp = q   + (size_t)(i0 + (tr<<2) + r) * DE + c0 + (tc<<2);
    float* kp = kk_ + (size_t)(i0 + (tr<<2) + r) * DE + c0 + (tc<<2);
    *(float4*)qp = make_float4(accq[r][0], accq[r][1], accq[r][2], accq[r][3]);
    *(float4*)kp = make_float4(acck[r][0], acck[r][1], acck[r][2], acck[r][3]);
  }
}

// ---------------------------------------------------------------------------
// 2) row squared norms
// ---------------------------------------------------------------------------
__global__ __launch_bounds__(256) void rownorm(
    const float* __restrict__ q, const float* __restrict__ kk_,
    float* __restrict__ q2, float* __restrict__ k2)
{
  int w = (blockIdx.x * 256 + threadIdx.x) >> 6;
  int lane = threadIdx.x & 63;
  const float* src = (w < NN) ? q : kk_;
  int row = (w < NN) ? w : w - NN;
  const float* p = src + (size_t)row * DE;
  float s = 0.f;
  for (int c = lane; c < DE; c += 64) { float v = p[c]; s += v * v; }
  for (int off = 32; off; off >>= 1) s += __shfl_down(s, off);
  if (lane == 0) { if (w < NN) q2[row] = s; else k2[row] = s; }
}

// ---------------------------------------------------------------------------
// 3) dots = (q2[i]+k2[j]-2*q@k^T)/DE
// ---------------------------------------------------------------------------
__global__ __launch_bounds__(256) void dots_gemm(
    const float* __restrict__ q, const float* __restrict__ kk_,
    const float* __restrict__ q2, const float* __restrict__ k2,
    float* __restrict__ dots)
{
  __shared__ float Qs[32][68], Ks[32][68];
  const int i0 = blockIdx.x * 64, j0 = blockIdx.y * 64;
  const int t = threadIdx.x, tr = t >> 4, tc = t & 15;
  float acc[4][4] = {};
  for (int kb = 0; kb < DE; kb += 32) {
    int m = t >> 3, k4 = (t & 7) << 2;
    {
      float4 v0 = ldg4(q + (size_t)(i0 + m) * DE + kb + k4);
      float4 v1 = ldg4(q + (size_t)(i0 + m + 32) * DE + kb + k4);
      Qs[k4+0][m] = v0.x; Qs[k4+1][m] = v0.y; Qs[k4+2][m] = v0.z; Qs[k4+3][m] = v0.w;
      Qs[k4+0][m+32] = v1.x; Qs[k4+1][m+32] = v1.y; Qs[k4+2][m+32] = v1.z; Qs[k4+3][m+32] = v1.w;
    }
    {
      float4 v0 = ldg4(kk_ + (size_t)(j0 + m) * DE + kb + k4);
      float4 v1 = ldg4(kk_ + (size_t)(j0 + m + 32) * DE + kb + k4);
      Ks[k4+0][m] = v0.x; Ks[k4+1][m] = v0.y; Ks[k4+2][m] = v0.z; Ks[k4+3][m] = v0.w;
      Ks[k4+0][m+32] = v1.x; Ks[k4+1][m+32] = v1.y; Ks[k4+2][m+32] = v1.z; Ks[k4+3][m+32] = v1.w;
    }
    __syncthreads();
    #pragma unroll
    for (int kkk = 0; kkk < 32; ++kkk) {
      float a[4], b[4];
      *(float4*)a = *(const float4*)&Qs[kkk][tr << 2];
      *(float4*)b = *(const float4*)&Ks[kkk][tc << 2];
      #pragma unroll
      for (int r = 0; r < 4; ++r)
        #pragma unroll
        for (int c = 0; c < 4; ++c) acc[r][c] += a[r]*b[c];
    }
    __syncthreads();
  }
  const float inv = 1.0f / (float)DE;
  float k2v[4]; *(float4*)k2v = ldg4(k2 + j0 + (tc<<2));
  #pragma unroll
  for (int r = 0; r < 4; ++r) {
    float q2v = q2[i0 + (tr<<2) + r];
    float o[4];
    #pragma unroll
    for (int c = 0; c < 4; ++c) o[c] = (q2v + k2v[c] - 2.0f*acc[r][c]) * inv;
    *(float4*)(dots + (size_t)(i0 + (tr<<2) + r) * NN + j0 + (tc<<2)) =
        make_float4(o[0], o[1], o[2], o[3]);
  }
}

// ---------------------------------------------------------------------------
// 4) per-row top-64 -> bit mask rows
// ---------------------------------------------------------------------------
__global__ __launch_bounds__(256) void topk_bits(
    const float* __restrict__ dots, unsigned int* __restrict__ bits)
{
  __shared__ float row[NN];
  __shared__ unsigned int b[128];
  __shared__ float rv[4]; __shared__ int ri[4];
  const int i = blockIdx.x, t = threadIdx.x;
  const float* dr = dots + (size_t)i * NN;
  for (int c = t; c < NN; c += 256) row[c] = dr[c];
  if (t < 128) b[t] = 0u;
  __syncthreads();
  for (int it = 0; it < 64; ++it) {
    float bv = -FLT_MAX; int bi = NN;
    for (int c = t; c < NN; c += 256) { float v = row[c]; if (v > bv) { bv = v; bi = c; } }
    for (int off = 32; off; off >>= 1) {
      float ov = __shfl_down(bv, off); int oi = __shfl_down(bi, off);
      if (ov > bv || (ov == bv && oi < bi)) { bv = ov; bi = oi; }
    }
    if ((t & 63) == 0) { rv[t >> 6] = bv; ri[t >> 6] = bi; }
    __syncthreads();
    if (t == 0) {
      float fv = rv[0]; int fi = ri[0];
      for (int w = 1; w < 4; ++w)
        if (rv[w] > fv || (rv[w] == fv && ri[w] < fi)) { fv = rv[w]; fi = ri[w]; }
      b[fi >> 5] |= 1u << (fi & 31);
      row[fi] = -FLT_MAX;
    }
    __syncthreads();
  }
  if (t < 128) bits[(size_t)i * 128 + t] = b[t];
}

// ---------------------------------------------------------------------------
// 5) A = I - alpha * dots * (bit(i,j)|bit(j,i)), in place over dots.
// ---------------------------------------------------------------------------
__global__ __launch_bounds__(256) void build_A(
    float* __restrict__ A, const unsigned int* __restrict__ bits,
    const float* __restrict__ alpha_p)
{
  int tid = blockIdx.x * 256 + threadIdx.x;
  int i = tid >> 10;
  int j4 = (tid & 1023) << 2;
  float alpha = alpha_p[0];
  float* p = A + (size_t)i * NN + j4;
  float4 d = *(float4*)p;
  unsigned int wrow = bits[(size_t)i * 128 + (j4 >> 5)];
  float dv[4] = {d.x, d.y, d.z, d.w}, o[4];
  #pragma unroll
  for (int u = 0; u < 4; ++u) {
    int j = j4 + u;
    unsigned int m1 = (wrow >> (j & 31)) & 1u;
    unsigned int m2 = (bits[(size_t)j * 128 + (i >> 5)] >> (i & 31)) & 1u;
    float base = (i == j) ? 1.0f : 0.0f;
    o[u] = base - ((m1 | m2) ? alpha * dv[u] : 0.0f);
  }
  *(float4*)p = make_float4(o[0], o[1], o[2], o[3]);
}

// ---------------------------------------------------------------------------
// 6) register-resident 16-col panel factorization with partial pivoting.
//    Virtual pivoting: only the perm_s entries swap; data stays put.
// ---------------------------------------------------------------------------
__device__ __forceinline__ void factor16(
    float (&a)[4][16], int k0f, int Mf,
    int* perm_s, float (&l11)[16][17],
    float* bufA, float* bufB, float* rv, int* ri, int* s_pr)
{
  const int t = threadIdx.x;
  #pragma unroll
  for (int j = 0; j < 16; ++j) {
    float bv = -1.0f; int br = 1 << 30;
    #pragma unroll
    for (int i = 0; i < 4; ++i) {
      int r = t + (i << 10);
      if (r >= j && r < Mf) {
        float v = fabsf(a[i][j]);
        if (v > bv || (v == bv && r < br)) { bv = v; br = r; }
      }
    }
    #pragma unroll
    for (int off = 32; off; off >>= 1) {
      float ov = __shfl_down(bv, off); int orr = __shfl_down(br, off);
      if (ov > bv || (ov == bv && orr < br)) { bv = ov; br = orr; }
    }
    if ((t & 63) == 0) { rv[t >> 6] = bv; ri[t >> 6] = br; }
    __syncthreads();
    if (t == 0) {
      float fv = rv[0]; int fr = ri[0];
      for (int w = 1; w < 16; ++w)
        if (rv[w] > fv || (rv[w] == fv && ri[w] < fr)) { fv = rv[w]; fr = ri[w]; }
      *s_pr = fr;
      if (fr != j) {
        int tmp = perm_s[k0f + j];
        perm_s[k0f + j] = perm_s[k0f + fr];
        perm_s[k0f + fr] = tmp;
      }
    }
    __syncthreads();
    const int pr = *s_pr, prT = pr & 1023, prS = pr >> 10;
    if (t == prT) {
      #pragma unroll
      for (int i2 = 0; i2 < 4; ++i2) if (i2 == prS) {
        #pragma unroll
        for (int c = 0; c < 16; ++c) bufB[c] = a[i2][c];
      }
    }
    if (t == j) {
      #pragma unroll
      for (int c = 0; c < 16; ++c) bufA[c] = a[0][c];
    }
    __syncthreads();
    if (t == j) {
      #pragma unroll
      for (int c = 0; c < 16; ++c) a[0][c] = bufB[c];
    }
    if (t == prT) {
      #pragma unroll
      for (int i2 = 0; i2 < 4; ++i2) if (i2 == prS) {
        #pragma unroll
        for (int c = 0; c < 16; ++c) a[i2][c] = bufA[c];
      }
    }
    float rp = 1.0f / bufB[j];
    #pragma unroll
    for (int i = 0; i < 4; ++i) {
      int r = t + (i << 10);
      if (r > j && r < Mf) {
        float mlt = a[i][j] * rp;
        a[i][j] = mlt;
        #pragma unroll
        for (int c = j + 1; c < 16; ++c) a[i][c] -= mlt * bufB[c];
      }
    }
    __syncthreads();
  }
  if (t < 16) {
    #pragma unroll
    for (int c = 0; c < 16; ++c) l11[t][c] = a[0][c];
  }
  __syncthreads();
}

// ---------------------------------------------------------------------------
// 7) whole LU as ONE cooperative kernel. 256 blocks x 1024 threads.
//    ROW-AT-A-TIME updates everywhere: worst-path live set ~100 VGPR -> no
//    scratch spill (round-3 failure mode: 160 live floats -> 200 GB scratch).
// ---------------------------------------------------------------------------
__global__ __launch_bounds__(1024, 4) void lu_coop(
    float* __restrict__ A, int* __restrict__ permg)
{
  __shared__ int perm_s[NN];          // block 0's authoritative perm (16 KB)
  __shared__ float l11s[16][17];
  __shared__ float u12s[16][20];      // row stride 20 -> 16B-aligned float4 rows
  __shared__ float bufA[16], bufB[16];
  __shared__ float rv[16]; __shared__ int ri[16];
  __shared__ int s_pr;

  const int t = threadIdx.x;
  const int b = blockIdx.x;
  cg::grid_group grid = cg::this_grid();
  float a[4][16];

  if (b == 0) {
    for (int r = t; r < NN; r += 1024) perm_s[r] = r;
    __syncthreads();
    #pragma unroll
    for (int i = 0; i < 4; ++i) {
      int r = t + (i << 10);
      const float* src = A + (size_t)r * NN;
      #pragma unroll
      for (int c4 = 0; c4 < 16; c4 += 4) {
        float4 v = ldg4(src + c4);
        a[i][c4] = v.x; a[i][c4+1] = v.y; a[i][c4+2] = v.z; a[i][c4+3] = v.w;
      }
    }
    factor16(a, 0, NN, perm_s, l11s, bufA, bufB, rv, ri, &s_pr);
    #pragma unroll
    for (int i = 0; i < 4; ++i) {
      int r = t + (i << 10);
      float* dst = A + (size_t)perm_s[r] * NN;
      #pragma unroll
      for (int c4 = 0; c4 < 16; c4 += 4)
        *(float4*)(dst + c4) = make_float4(a[i][c4], a[i][c4+1], a[i][c4+2], a[i][c4+3]);
    }
    for (int r = t; r < NN; r += 1024) permg[r] = perm_s[r];   // buf0 = panel-0 state
  }
  __threadfence();
  grid.sync();

  for (int p = 0; p < NPAN - 1; ++p) {
    const int k0 = p << 4, kS = k0 + 16, M2 = NN - kS;
    if (b == 0) {
      // --- trsm for the lookahead strip cols [kS, kS+16) ---
      if (t < 256) {
        int jj = t >> 4, cc = t & 15;
        u12s[jj][cc] = A[(size_t)perm_s[k0 + jj] * NN + kS + cc];
      }
      __syncthreads();
      if (t < 16) {
        float x[16];
        #pragma unroll
        for (int j = 0; j < 16; ++j) x[j] = u12s[j][t];
        #pragma unroll
        for (int j = 1; j < 16; ++j) {
          float s = x[j];
          #pragma unroll
          for (int jj = 0; jj < 16; ++jj) if (jj < j) s -= l11s[j][jj] * x[jj];
          x[j] = s;
        }
        #pragma unroll
        for (int j = 0; j < 16; ++j) {
          u12s[j][t] = x[j];
          A[(size_t)perm_s[k0 + j] * NN + kS + t] = x[j];
        }
      }
      __syncthreads();
      // --- rank-16 update of the strip, ROW AT A TIME, into regs a ---
      #pragma unroll
      for (int i = 0; i < 4; ++i) {
        int rr = t + (i << 10);
        if (rr < M2) {
          size_t ph = (size_t)perm_s[kS + rr];
          const float* Lp = A + ph * NN + k0;
          const float* Cp = A + ph * NN + kS;
          float L[16];
          #pragma unroll
          for (int c4 = 0; c4 < 16; c4 += 4) {
            float4 lv = ldg4(Lp + c4);
            L[c4]=lv.x; L[c4+1]=lv.y; L[c4+2]=lv.z; L[c4+3]=lv.w;
            float4 cv = ldg4(Cp + c4);
            a[i][c4]=cv.x; a[i][c4+1]=cv.y; a[i][c4+2]=cv.z; a[i][c4+3]=cv.w;
          }
          #pragma unroll
          for (int j = 0; j < 16; ++j) {
            float lj = L[j];
            #pragma unroll
            for (int c4 = 0; c4 < 16; c4 += 4) {
              float4 u4 = *(const float4*)&u12s[j][c4];
              a[i][c4]   -= lj * u4.x;
              a[i][c4+1] -= lj * u4.y;
              a[i][c4+2] -= lj * u4.z;
              a[i][c4+3] -= lj * u4.w;
            }
          }
        }
      }
      // --- factor panel p+1 in registers ---
      factor16(a, kS, M2, perm_s, l11s, bufA, bufB, rv, ri, &s_pr);
      // --- writeback factored strip ---
      #pragma unroll
      for (int i = 0; i < 4; ++i) {
        int rr = t + (i << 10);
        if (rr < M2) {
          float* dst = A + (size_t)perm_s[kS + rr] * NN + kS;
          #pragma unroll
          for (int c4 = 0; c4 < 16; c4 += 4)
            *(float4*)(dst + c4) = make_float4(a[i][c4], a[i][c4+1], a[i][c4+2], a[i][c4+3]);
        }
      }
      // --- publish panel (p+1) perm state to the other buffer ---
      int* dstp = permg + (((p + 1) & 1) ? NN : 0);
      for (int r = t; r < NN; r += 1024) dstp[r] = perm_s[r];
    } else {
      const int* pg = permg + ((p & 1) ? NN : 0);   // panel-p perm state
      for (int cb = b - 1; ; cb += (GBLK - 1)) {
        int c0 = k0 + 32 + cb * 16;
        if (c0 >= NN) break;
        // stage L11 + raw A12 chunk, then local trsm (redundant, tiny)
        if (t < 256) {
          int jj = t >> 4, cc = t & 15;
          int prw = pg[k0 + jj];
          l11s[jj][cc] = A[(size_t)prw * NN + k0 + cc];
          u12s[jj][cc] = A[(size_t)prw * NN + c0 + cc];
        }
        __syncthreads();
        if (t < 16) {
          float x[16];
          #pragma unroll
          for (int j = 0; j < 16; ++j) x[j] = u12s[j][t];
          #pragma unroll
          for (int j = 1; j < 16; ++j) {
            float s = x[j];
            #pragma unroll
            for (int jj = 0; jj < 16; ++jj) if (jj < j) s -= l11s[j][jj] * x[jj];
            x[j] = s;
          }
          #pragma unroll
          for (int j = 0; j < 16; ++j) {
            u12s[j][t] = x[j];
            A[(size_t)pg[k0 + j] * NN + c0 + t] = x[j];
          }
        }
        __syncthreads();
        // --- C chunk update, ROW AT A TIME (live set ~45 regs) ---
        #pragma unroll
        for (int i = 0; i < 4; ++i) {
          int rr = t + (i << 10);
          if (rr < M2) {
            size_t ph = (size_t)pg[kS + rr];
            const float* Lp = A + ph * NN + k0;
            float* Cp = A + ph * NN + c0;
            float L[16], C[16];
            #pragma unroll
            for (int c4 = 0; c4 < 16; c4 += 4) {
              float4 lv = ldg4(Lp + c4);
              L[c4]=lv.x; L[c4+1]=lv.y; L[c4+2]=lv.z; L[c4+3]=lv.w;
              float4 cv = ldg4(Cp + c4);
              C[c4]=cv.x; C[c4+1]=cv.y; C[c4+2]=cv.z; C[c4+3]=cv.w;
            }
            #pragma unroll
            for (int j = 0; j < 16; ++j) {
              float lj = L[j];
              #pragma unroll
              for (int c4 = 0; c4 < 16; c4 += 4) {
                float4 u4 = *(const float4*)&u12s[j][c4];
                C[c4]   -= lj * u4.x;
                C[c4+1] -= lj * u4.y;
                C[c4+2] -= lj * u4.z;
                C[c4+3] -= lj * u4.w;
              }
            }
            #pragma unroll
            for (int c4 = 0; c4 < 16; c4 += 4)
              *(float4*)(Cp + c4) = make_float4(C[c4], C[c4+1], C[c4+2], C[c4+3]);
          }
        }
        __syncthreads();
      }
    }
    __threadfence();
    grid.sync();
  }
}

// ---------------------------------------------------------------------------
// 8) invert the 32 diagonal 128x128 blocks of L (unit lower) / U (upper),
//    reading A rows through the final perm.
// ---------------------------------------------------------------------------
__global__ __launch_bounds__(128) void inv_tri(
    const float* __restrict__ Ag, const int* __restrict__ perm,
    float* __restrict__ invT, int upper)
{
  __shared__ float xs[128][128];
  const int s = blockIdx.x, t = threadIdx.x;
  const int r0 = s * SB;
  for (int i = 0; i < 128; ++i) xs[i][t] = 0.0f;
  if (!upper) {
    xs[t][t] = 1.0f;
    for (int i = 1; i < 128; ++i) {
      const float* Ti = Ag + (size_t)perm[r0 + i] * NN + r0;
      float ssum = 0.f;
      for (int j = 0; j < i; ++j) ssum += Ti[j] * xs[j][t];
      if (i != t) xs[i][t] = -ssum;
    }
  } else {
    { const float* Tt = Ag + (size_t)perm[r0 + t] * NN + r0; xs[t][t] = 1.0f / Tt[t]; }
    for (int i = 126; i >= 0; --i) {
      const float* Ti = Ag + (size_t)perm[r0 + i] * NN + r0;
      float ssum = 0.f;
      for (int j = i + 1; j < 128; ++j) ssum += Ti[j] * xs[j][t];
      if (i != t) xs[i][t] = -ssum / Ti[i];
    }
  }
  for (int i = 0; i < 128; ++i) invT[(size_t)s * SB * SB + (size_t)i * SB + t] = xs[i][t];
}

// ---------------------------------------------------------------------------
// 9) C -= A(perm rows) * B   (64x64 tile, KT=32; K multiple of 32).
// ---------------------------------------------------------------------------
__global__ __launch_bounds__(256) void rank_update(
    float* __restrict__ C, int ldc,
    const float* __restrict__ Ab, int rowoff, int coloff,
    const int* __restrict__ perm,
    const float* __restrict__ Bop, int ldb,
    int Mr, int Nc, int K)
{
  __shared__ float As[32][68], Bs[32][68];
  const int m0 = blockIdx.x * 64, n0 = blockIdx.y * 64;
  const int t = threadIdx.x, tr = t >> 4, tc = t & 15;
  const float4 z4 = make_float4(0.f, 0.f, 0.f, 0.f);
  float acc[4][4] = {};
  for (int kb = 0; kb < K; kb += 32) {
    {
      int m = t >> 3, k4 = (t & 7) << 2;
      int row0 = m0 + m, row1 = m0 + m + 32;
      float4 v0 = z4, v1 = z4;
      if (row0 < Mr) v0 = ldg4(Ab + (size_t)perm[rowoff + row0] * NN + coloff + kb + k4);
      if (row1 < Mr) v1 = ldg4(Ab + (size_t)perm[rowoff + row1] * NN + coloff + kb + k4);
      As[k4+0][m] = v0.x; As[k4+1][m] = v0.y; As[k4+2][m] = v0.z; As[k4+3][m] = v0.w;
      As[k4+0][m+32] = v1.x; As[k4+1][m+32] = v1.y; As[k4+2][m+32] = v1.z; As[k4+3][m+32] = v1.w;
    }
    {
      int kr = t >> 3, n8 = (t & 7) << 3;
      bool ok = (n0 + n8 < Nc);
      float4 w0 = ok ? ldg4(Bop + (size_t)(kb + kr) * ldb + n0 + n8) : z4;
      float4 w1 = ok ? ldg4(Bop + (size_t)(kb + kr) * ldb + n0 + n8 + 4) : z4;
      *(float4*)&Bs[kr][n8] = w0; *(float4*)&Bs[kr][n8+4] = w1;
    }
    __syncthreads();
    #pragma unroll
    for (int kkk = 0; kkk < 32; ++kkk) {
      float av[4], bvv[4];
      *(float4*)av = *(const float4*)&As[kkk][tr << 2];
      *(float4*)bvv = *(const float4*)&Bs[kkk][tc << 2];
      #pragma unroll
      for (int r = 0; r < 4; ++r)
        #pragma unroll
        for (int c = 0; c < 4; ++c) acc[r][c] += av[r] * bvv[c];
    }
    __syncthreads();
  }
  #pragma unroll
  for (int r = 0; r < 4; ++r) {
    int m = m0 + (tr << 2) + r;
    int n = n0 + (tc << 2);
    if (m < Mr && n < Nc) {
      float* cp = C + (size_t)m * ldc + n;
      float4 cv = *(float4*)cp;
      cv.x -= acc[r][0]; cv.y -= acc[r][1]; cv.z -= acc[r][2]; cv.w -= acc[r][3];
      *(float4*)cp = cv;
    }
  }
}

// 10) out[r][:] = xf[perm[r]][:]  (RHS permutation P b)
__global__ __launch_bounds__(256) void gather_rows(
    const float* __restrict__ xf, const int* __restrict__ perm, float* __restrict__ out)
{
  const int r = blockIdx.x, t = threadIdx.x;
  const int src = perm[r];
  const float4* s = (const float4*)(xf + (size_t)src * DD);
  float4* d = (float4*)(out + (size_t)r * DD);
  for (int c = t; c < DD / 4; c += 256) d[c] = s[c];
}

// ---------------------------------------------------------------------------
// 11) in-place diag block apply: B[r0:r0+128, :] = Minv(128x128) @ same.
// ---------------------------------------------------------------------------
__global__ __launch_bounds__(256) void diag_apply(
    float* __restrict__ B, const float* __restrict__ Minv, int r0)
{
  __shared__ float Bs[128][68];
  const int c0 = blockIdx.x * 64, t = threadIdx.x;
  #pragma unroll
  for (int v = 0; v < 8; ++v) {
    int id = t + v * 256;
    int k = id >> 4, c4 = (id & 15) << 2;
    *(float4*)&Bs[k][c4] = ldg4(B + (size_t)(r0 + k) * DD + c0 + c4);
  }
  __syncthreads();
  const int tr = t >> 4, tc = t & 15;
  float acc[8][4] = {};
  for (int k4 = 0; k4 < 128; k4 += 4) {
    float b0[4], b1[4], b2[4], b3[4];
    *(float4*)b0 = *(const float4*)&Bs[k4+0][tc << 2];
    *(float4*)b1 = *(const float4*)&Bs[k4+1][tc << 2];
    *(float4*)b2 = *(const float4*)&Bs[k4+2][tc << 2];
    *(float4*)b3 = *(const float4*)&Bs[k4+3][tc << 2];
    #pragma unroll
    for (int rr = 0; rr < 8; ++rr) {
      float m[4]; *(float4*)m = ldg4(Minv + (size_t)(tr*8 + rr) * SB + k4);
      #pragma unroll
      for (int c = 0; c < 4; ++c)
        acc[rr][c] += m[0]*b0[c] + m[1]*b1[c] + m[2]*b2[c] + m[3]*b3[c];
    }
  }
  #pragma unroll
  for (int rr = 0; rr < 8; ++rr)
    *(float4*)(B + (size_t)(r0 + tr*8 + rr) * DD + c0 + (tc << 2)) =
        make_float4(acc[rr][0], acc[rr][1], acc[rr][2], acc[rr][3]);
}

// ---------------------------------------------------------------------------
extern "C" void kernel_launch(void* const* d_in, const int* in_sizes, int n_in,
                              void* d_out, int out_size, void* d_ws, size_t ws_size,
                              hipStream_t stream)
{
  const float* xf    = (const float*)d_in[0];
  const float* Wq    = (const float*)d_in[1];
  const float* Wk    = (const float*)d_in[2];
  const float* alpha = (const float*)d_in[3];
  float* out = (float*)d_out;
  char* ws = (char*)d_ws;

  // workspace layout
  float* Amat = (float*)(ws);                          // 64 MB (dots -> A -> LU)
  float* q    = (float*)(ws + 67108864ull);            // 8 MB
  float* kbuf = (float*)(ws + 75497472ull);            // 8 MB
  float* invL = (float*)(ws + 83886080ull);            // 2 MB
  float* invU = (float*)(ws + 85983232ull);            // 2 MB
  unsigned int* bits = (unsigned int*)(ws + 88080384ull); // 2 MB
  float* q2   = (float*)(ws + 90177536ull);
  float* k2   = (float*)(ws + 90193920ull);
  int* permg  = (int*)(ws + 90210304ull);              // 2 x NN ints (ping-pong)
  int* permF  = permg + NN;                            // final = panel-255 state (odd)

  proj_gemm<<<dim3(NN/64, DE/64), 256, 0, stream>>>(xf, Wq, Wk, q, kbuf);
  rownorm<<<2 * NN / 4, 256, 0, stream>>>(q, kbuf, q2, k2);
  dots_gemm<<<dim3(NN/64, NN/64), 256, 0, stream>>>(q, kbuf, q2, k2, Amat);
  topk_bits<<<NN, 256, 0, stream>>>(Amat, bits);
  build_A<<<NN * NN / 4 / 256, 256, 0, stream>>>(Amat, bits, alpha);

  // the entire pivoted LU in one cooperative kernel
  {
    float* Ap = Amat; int* Pp = permg;
    void* kargs[] = { (void*)&Ap, (void*)&Pp };
    hipLaunchCooperativeKernel(reinterpret_cast<void*>(lu_coop),
                               dim3(GBLK), dim3(1024), kargs, 0, stream);
  }

  inv_tri<<<NSB, 128, 0, stream>>>(Amat, permF, invL, 0);
  inv_tri<<<NSB, 128, 0, stream>>>(Amat, permF, invU, 1);
  gather_rows<<<NN, 256, 0, stream>>>(xf, permF, out);

  // forward solve L y = P b
  for (int s = 0; s < NSB; ++s) {
    int r0 = s * SB;
    diag_apply<<<DD / 64, 256, 0, stream>>>(out, invL + (size_t)s * SB * SB, r0);
    if (r0 + SB < NN) {
      int M2 = NN - r0 - SB;
      rank_update<<<dim3(M2 / 64, DD / 64), 256, 0, stream>>>(
          out + (size_t)(r0 + SB) * DD, DD,
          Amat, r0 + SB, r0, permF,
          out + (size_t)r0 * DD, DD,
          M2, DD, SB);
    }
  }
  // backward solve U x = y
  for (int s = NSB - 1; s >= 0; --s) {
    int r0 = s * SB;
    diag_apply<<<DD / 64, 256, 0, stream>>>(out, invU + (size_t)s * SB * SB, r0);
    if (r0 > 0) {
      rank_update<<<dim3(r0 / 64, DD / 64), 256, 0, stream>>>(
          out, DD,
          Amat, 0, r0, permF,
          out + (size_t)r0 * DD, DD,
          r0, DD, SB);
    }
  }
}